// Round 1
// baseline (18187.914 us; speedup 1.0000x reference)
//
#include <hip/hip_runtime.h>

#define HIDDEN   2048
#define T_STEPS  8192
#define WASHOUT  200
#define NWG      64
#define NTHR     512
#define NWAVE    (NTHR / 64)                 // 8 waves
#define ROWS_PER_WG   (HIDDEN / NWG)         // 32
#define ROWS_PER_WAVE (ROWS_PER_WG / NWAVE)  // 4
#define NCHUNK   8                           // 8 chunks of 256 state elements

// ws layout: unsigned long long pairs[2][HIDDEN] -- {value:hi32, step:lo32}.
// One 8B unit carries payload+tag: no fences, no flags, one round trip.
// 0xAA poison: step field 0xAAAAAAAA never matches a real step (self-init).

// R14 change: weights moved AGPR -> VGPR. gfx950 VALU cannot source AGPRs,
// so the AGPR scheme cost 2 VALU instrs per FMA (v_accvgpr_read + v_fmac).
// At 512 thr (2 waves/SIMD) the unified-file budget is 256 regs/thread:
// 128 weight VGPRs + ~60 working VGPRs fit, so plain v_fmac_f32 w/ VGPR
// weights halves the inner-loop instruction count. The empty "+v" asm pins
// each weight in a VGPR and makes it opaque (no refetch/remat in t-loop).

// DPP add: x + dpp_perm(x). All-VALU (no DS round trip).
#define DPP_ADD(x, ctrl) ((x) + __int_as_float(__builtin_amdgcn_update_dpp( \
    0, __float_as_int(x), ctrl, 0xF, 0xF, true)))

typedef unsigned uint4v __attribute__((ext_vector_type(4)));

__global__ __launch_bounds__(NTHR, 1) void esn_main(
    const float* __restrict__ u,
    const float* __restrict__ w_in,
    const float* __restrict__ w_res,
    const float* __restrict__ w_out,
    float* __restrict__ out,
    unsigned long long* __restrict__ pairs)
{
  const int g  = blockIdx.x;    // 0..63, one WG per CU
  const int j  = threadIdx.x;   // 0..511
  const int wv = j >> 6;        // 0..7
  const int l  = j & 63;

  __shared__ float x_s[2][HIDDEN];      // double-buffered staged state (16 KB)
  __shared__ float u_s[T_STEPS];        // 32 KB
  __shared__ float fresh[ROWS_PER_WG];  // this WG's newest 32 values

#pragma unroll
  for (int k = 0; k < T_STEPS / NTHR; ++k) u_s[j + NTHR * k] = u[j + NTHR * k];

  // wave wv owns rows r0..r0+3; lane l owns cols {c*256 + 4l .. +3}
  const int r0 = g * ROWS_PER_WG + wv * ROWS_PER_WAVE;

  float wreg[ROWS_PER_WAVE][4 * NCHUNK];  // 128 VGPR-resident weights/thread
#pragma unroll
  for (int i = 0; i < ROWS_PER_WAVE; ++i) {
#pragma unroll
    for (int c = 0; c < NCHUNK; ++c) {
      const float4 a = *(const float4*)&w_res[(r0 + i) * HIDDEN + c * 256 + 4 * l];
      wreg[i][4 * c + 0] = a.x; wreg[i][4 * c + 1] = a.y;
      wreg[i][4 * c + 2] = a.z; wreg[i][4 * c + 3] = a.w;
    }
  }
  // pin weights in VGPRs; value becomes opaque -> no refetch, no remat
#pragma unroll
  for (int i = 0; i < ROWS_PER_WAVE; ++i)
#pragma unroll
    for (int k = 0; k < 4 * NCHUNK; ++k)
      asm volatile("" : "+v"(wreg[i][k]));

  const float winl = w_in[r0 + (l & 3)];                             // lanes 0..3
  const float wol  = (wv == 1 && l < 32) ? w_out[g * 32 + l] : 0.f;  // wave 1

  __syncthreads();  // u_s ready

  for (int t = 0; t < T_STEPS; ++t) {
    float d0 = 0.f, d1 = 0.f, d2 = 0.f, d3 = 0.f;
    const unsigned b = (unsigned)((t - 1) & 1);
    if (t > 0) {
      const unsigned want = (unsigned)(t - 1);
      // wave wv polls only its own chunk; 2x16B L2-bypassing loads per round
      const unsigned long long* bp = pairs + b * HIDDEN + (wv << 8) + 4 * l;
      uint4v A, B;   // [tag0, val0, tag1, val1]
      for (;;) {
        asm volatile(
            "global_load_dwordx4 %0, %2, off sc1\n\t"
            "global_load_dwordx4 %1, %3, off sc1\n\t"
            "s_waitcnt vmcnt(0)"
            : "=&v"(A), "=&v"(B)
            : "v"(bp), "v"(bp + 2)
            : "memory");
        if (((A.x == want) & (A.z == want)) &
            ((B.x == want) & (B.z == want))) break;
      }
      float4 xv;
      xv.x = __uint_as_float(A.y);
      xv.y = __uint_as_float(A.w);
      xv.z = __uint_as_float(B.y);
      xv.w = __uint_as_float(B.w);
      *(float4*)&x_s[b][(wv << 8) + 4 * l] = xv;  // one ds_write_b128
    }
    __syncthreads();  // barrier 1: all chunks staged

    if (t > 0) {
      const float4* xs4 = (const float4*)x_s[b];
#define ROWFMA(i, di)                            \
      di = fmaf(wreg[i][4*c+0], x4.x, di);       \
      di = fmaf(wreg[i][4*c+1], x4.y, di);       \
      di = fmaf(wreg[i][4*c+2], x4.z, di);       \
      di = fmaf(wreg[i][4*c+3], x4.w, di);
#pragma unroll
      for (int c = 0; c < NCHUNK; ++c) {
        const float4 x4 = xs4[(c << 6) + l];   // ds_read_b128
        ROWFMA(0, d0)
        ROWFMA(1, d1)
        ROWFMA(2, d2)
        ROWFMA(3, d3)
      }
#undef ROWFMA
    }

    // reduce: DPP for intra-16 steps (VALU latency), shuffles only for 16/32.
    // quad sums -> selects -> row_ror:4 + row_ror:8 give per-16-group sums,
    // then 2 shuffles complete the 64-lane row sums (same placement as R9).
    float e0 = DPP_ADD(d0, 0xB1);   // quad_perm [1,0,3,2]  (xor 1)
    float e1 = DPP_ADD(d1, 0xB1);
    float e2 = DPP_ADD(d2, 0xB1);
    float e3 = DPP_ADD(d3, 0xB1);
    float f0 = (l & 1) ? e1 : e0;
    float f1 = (l & 1) ? e3 : e2;
    f0 = DPP_ADD(f0, 0x4E);         // quad_perm [2,3,0,1]  (xor 2)
    f1 = DPP_ADD(f1, 0x4E);
    float h = (l & 2) ? f1 : f0;
    h = DPP_ADD(h, 0x124);          // row_ror:4
    h = DPP_ADD(h, 0x128);          // row_ror:8
    h += __shfl_xor(h, 16, 64);
    h += __shfl_xor(h, 32, 64);

    const float ut = u_s[t];
    if (l < ROWS_PER_WAVE) {
      const float v = tanhf(fmaf(winl, ut, h));
      // R14 change: per-wave EARLY publish -- 4 lanes, 8B each, issued the
      // moment this wave's rows exist. Consumers' detect-latency clock starts
      // before barrier 2, so barrier 2 + readout hide under the store flight.
      // Safety: slot(t) == slot(t-2); overwriting requires this wave read all
      // tags t-1, which requires every wave consumed t-2. Invariant holds.
      const unsigned long long pk =
          ((unsigned long long)__float_as_uint(v) << 32) | (unsigned)t;
      __hip_atomic_store(pairs + (t & 1) * HIDDEN + r0 + l, pk,
                         __ATOMIC_RELAXED, __HIP_MEMORY_SCOPE_AGENT);
      fresh[wv * ROWS_PER_WAVE + l] = v;
    }
    __syncthreads();  // barrier 2: fresh[] complete (readout only)

    if (wv == 1 && t >= WASHOUT) {
      // distributed readout: this WG's 32-row partial of x_t . w_out
      float part = (l < 32) ? fresh[l] * wol : 0.f;
      part += __shfl_xor(part, 32, 64);
      part += __shfl_xor(part, 16, 64);
      part += __shfl_xor(part, 8, 64);
      part += __shfl_xor(part, 4, 64);
      part += __shfl_xor(part, 2, 64);
      part += __shfl_xor(part, 1, 64);
      if (l == 0) atomicAdd(&out[t - WASHOUT], part);
    }
  }
}

extern "C" void kernel_launch(void* const* d_in, const int* in_sizes, int n_in,
                              void* d_out, int out_size, void* d_ws, size_t ws_size,
                              hipStream_t stream) {
  const float* u     = (const float*)d_in[0];
  const float* w_in  = (const float*)d_in[1];
  const float* w_res = (const float*)d_in[2];
  const float* w_out = (const float*)d_in[3];
  float* out = (float*)d_out;
  unsigned long long* pairs = (unsigned long long*)d_ws;

  // out accumulates atomicAdd partials -> must start at zero every call
  hipMemsetAsync(out, 0, (size_t)out_size * sizeof(float), stream);
  esn_main<<<NWG, NTHR, 0, stream>>>(u, w_in, w_res, w_out, out, pairs);
}